// Round 4
// baseline (721.202 us; speedup 1.0000x reference)
//
#include <hip/hip_runtime.h>

#define KC 24
#define DC 128
#define TPB 256
#define NROWS 524288
#define RPB 256            // rows per block (4 waves x 64)
#define NGRP 8             // row-groups (of 8) per wave

#define ACC_FLOATS (KC * DC + KC + 1)

__global__ void vq_zero_acc(float* __restrict__ acc) {
    int i = blockIdx.x * blockDim.x + threadIdx.x;
    if (i < ACC_FLOATS) acc[i] = 0.0f;
}

__global__ __launch_bounds__(TPB) void vq_main(
    const float* __restrict__ z_e, const float* __restrict__ cb,
    float* __restrict__ o_soft, float* __restrict__ o_hard,
    float* __restrict__ o_idx, float* __restrict__ o_w,
    float* __restrict__ acc)
{
    __shared__ float cb_s[KC][DC + 4];
    __shared__ float wn_s[KC];
    __shared__ float ebin[KC][DC + 4];
    __shared__ float cnt_s[KC];
    __shared__ float loss_s;

    const int tid = threadIdx.x;
    const int w   = tid >> 6;
    const int l   = tid & 63;
    const int rg  = l >> 3;        // row within group of 8
    const int sub = l & 7;         // 8 lanes cooperate on one row
    const int sb4 = sub * 4;

    #pragma unroll 1
    for (int i = tid; i < KC * DC; i += TPB) cb_s[i >> 7][i & (DC - 1)] = cb[i];
    #pragma unroll 1
    for (int i = tid; i < KC * (DC + 4); i += TPB) (&ebin[0][0])[i] = 0.0f;
    if (tid < KC) cnt_s[tid] = 0.0f;
    if (tid == 0) loss_s = 0.0f;
    __syncthreads();
    if (tid < KC) {
        float s = 0.0f;
        #pragma unroll 1
        for (int d = 0; d < DC; ++d) s = fmaf(cb_s[tid][d], cb_s[tid][d], s);
        wn_s[tid] = s;
    }
    __syncthreads();

    const int rbase = blockIdx.x * RPB + w * 64;
    const float* gz = z_e + (size_t)rbase * DC;

    float loss_acc = 0.0f;

    // per-lane z segment: floats {sb4+i*32 .. sb4+i*32+3}, i=0..3
    float4 cur[4], nxt[4];
    #pragma unroll
    for (int i = 0; i < 4; ++i)
        nxt[i] = *(const float4*)(gz + (size_t)rg * DC + i * 32 + sb4);

    #pragma unroll 1
    for (int g = 0; g < NGRP; ++g) {
        #pragma unroll
        for (int i = 0; i < 4; ++i) cur[i] = nxt[i];
        if (g + 1 < NGRP) {
            #pragma unroll
            for (int i = 0; i < 4; ++i)
                nxt[i] = *(const float4*)(gz + (size_t)((g + 1) * 8 + rg) * DC
                                          + i * 32 + sb4);
        }

        float zn = 0.0f;
        #pragma unroll
        for (int i = 0; i < 4; ++i)
            zn = fmaf(cur[i].x, cur[i].x, fmaf(cur[i].y, cur[i].y,
                 fmaf(cur[i].z, cur[i].z, fmaf(cur[i].w, cur[i].w, zn))));

        float dv[KC];
        #pragma unroll
        for (int k = 0; k < KC; ++k) {
            float s = 0.0f;
            #pragma unroll
            for (int i = 0; i < 4; ++i) {
                const float4 wv = *(const float4*)(&cb_s[k][i * 32 + sb4]);
                s = fmaf(cur[i].x, wv.x, fmaf(cur[i].y, wv.y,
                    fmaf(cur[i].z, wv.z, fmaf(cur[i].w, wv.w, s))));
            }
            dv[k] = s;
        }
        // 8-lane tree reduce (masks 1,2,4 stay within the 8-lane group)
        #pragma unroll
        for (int m = 1; m <= 4; m <<= 1) {
            zn += __shfl_xor(zn, m);
            #pragma unroll
            for (int k = 0; k < KC; ++k) dv[k] += __shfl_xor(dv[k], m);
        }

        // dists, argmin (first-min), softmax — replicated in the 8 lanes
        int idx = 0;
        float best = 3.4e38f;
        #pragma unroll
        for (int k = 0; k < KC; ++k) {
            float d = (zn - 2.0f * dv[k]) + wn_s[k];
            dv[k] = d;
            if (d < best) { best = d; idx = k; }
        }
        float ssum = 0.0f;
        #pragma unroll
        for (int k = 0; k < KC; ++k) {
            float e = __expf(best - dv[k]);
            dv[k] = e;
            ssum += e;
        }
        const float inv = 1.0f / ssum;
        #pragma unroll
        for (int k = 0; k < KC; ++k) dv[k] *= inv;   // weights, replicated

        const int row = rbase + g * 8 + rg;

        // weights: lanes sub<6 store one float4 each -> 768B contiguous per group
        {
            float4 wq;
            switch (sub) {
                case 0:  wq = make_float4(dv[0],  dv[1],  dv[2],  dv[3]);  break;
                case 1:  wq = make_float4(dv[4],  dv[5],  dv[6],  dv[7]);  break;
                case 2:  wq = make_float4(dv[8],  dv[9],  dv[10], dv[11]); break;
                case 3:  wq = make_float4(dv[12], dv[13], dv[14], dv[15]); break;
                case 4:  wq = make_float4(dv[16], dv[17], dv[18], dv[19]); break;
                default: wq = make_float4(dv[20], dv[21], dv[22], dv[23]); break;
            }
            if (sub < 6)
                *(float4*)(o_w + (size_t)row * KC + sb4) = wq;
        }
        if (sub == 0) {
            o_idx[row] = (float)idx;
            loss_acc += best;
            atomicAdd(&cnt_s[idx], 1.0f);
        }

        // z_q_soft segment: q = sum_k w[k] * cb[k][seg]
        float4 q[4];
        #pragma unroll
        for (int i = 0; i < 4; ++i) q[i] = make_float4(0.f, 0.f, 0.f, 0.f);
        #pragma unroll
        for (int k = 0; k < KC; ++k) {
            const float wk = dv[k];
            #pragma unroll
            for (int i = 0; i < 4; ++i) {
                const float4 wv = *(const float4*)(&cb_s[k][i * 32 + sb4]);
                q[i].x = fmaf(wk, wv.x, q[i].x);
                q[i].y = fmaf(wk, wv.y, q[i].y);
                q[i].z = fmaf(wk, wv.z, q[i].z);
                q[i].w = fmaf(wk, wv.w, q[i].w);
            }
        }
        #pragma unroll
        for (int i = 0; i < 4; ++i)
            *(float4*)(o_soft + (size_t)row * DC + i * 32 + sb4) = q[i];

        // z_q_hard segment straight from LDS codebook
        #pragma unroll
        for (int i = 0; i < 4; ++i) {
            const float4 h = *(const float4*)(&cb_s[idx][i * 32 + sb4]);
            *(float4*)(o_hard + (size_t)row * DC + i * 32 + sb4) = h;
        }

        // ebin: lane adds its retained z segment (no z reload)
        #pragma unroll
        for (int i = 0; i < 4; ++i) {
            const int d = i * 32 + sb4;
            atomicAdd(&ebin[idx][d + 0], cur[i].x);
            atomicAdd(&ebin[idx][d + 1], cur[i].y);
            atomicAdd(&ebin[idx][d + 2], cur[i].z);
            atomicAdd(&ebin[idx][d + 3], cur[i].w);
        }
    }

    // loss: wave reduce -> one LDS atomic per wave
    #pragma unroll
    for (int off = 32; off > 0; off >>= 1) loss_acc += __shfl_down(loss_acc, off);
    if (l == 0) atomicAdd(&loss_s, loss_acc);
    __syncthreads();

    #pragma unroll 1
    for (int i = tid; i < KC * DC; i += TPB)
        atomicAdd(&acc[i], ebin[i >> 7][i & (DC - 1)]);
    if (tid < KC) atomicAdd(&acc[KC * DC + tid], cnt_s[tid]);
    if (tid == 0) atomicAdd(&acc[KC * DC + KC], loss_s);
}

__global__ void vq_epilogue(
    const float* __restrict__ z_e, const float* __restrict__ ema_cs,
    const float* __restrict__ ema_es, const int* __restrict__ rand_idx,
    const float* __restrict__ acc,
    float* __restrict__ o_loss, float* __restrict__ o_cbn,
    float* __restrict__ o_ecs, float* __restrict__ o_ees)
{
    __shared__ float ecs_s[KC], sm_s[KC];
    __shared__ float n_sh;
    const int tid = threadIdx.x;
    if (tid < KC) ecs_s[tid] = 0.95f * ema_cs[tid] + 0.05f * acc[KC * DC + tid];
    __syncthreads();
    if (tid == 0) {
        float n = 0.0f;
        for (int k = 0; k < KC; ++k) n += ecs_s[k];
        n_sh = n;
    }
    __syncthreads();
    if (tid < KC) {
        float n = n_sh;
        sm_s[tid] = (ecs_s[tid] + 1e-5f) / (n + (float)KC * 1e-5f) * n;
    }
    __syncthreads();
    #pragma unroll 1
    for (int i = tid; i < KC * DC; i += TPB) {
        int k = i >> 7, d = i & (DC - 1);
        float ees = 0.95f * ema_es[i] + 0.05f * acc[i];
        float cbn = ees / sm_s[k];
        bool dead = ecs_s[k] < 0.1f;
        float rst = z_e[(size_t)rand_idx[k] * DC + d];
        o_cbn[i] = dead ? rst : cbn;
        o_ees[i] = dead ? rst : ees;
    }
    if (tid < KC) o_ecs[tid] = (ecs_s[tid] < 0.1f) ? 1.0f : ecs_s[tid];
    if (tid == 0) o_loss[0] = 1.5f * (acc[KC * DC + KC] * (1.0f / 67108864.0f));
}

extern "C" void kernel_launch(void* const* d_in, const int* in_sizes, int n_in,
                              void* d_out, int out_size, void* d_ws, size_t ws_size,
                              hipStream_t stream) {
    const float* z_e    = (const float*)d_in[0];
    const float* cb     = (const float*)d_in[1];
    const float* ema_cs = (const float*)d_in[2];
    const float* ema_es = (const float*)d_in[3];
    const int*   ridx   = (const int*)d_in[4];

    float* out = (float*)d_out;
    float* o_soft = out;                                  // 67108864
    float* o_hard = out + 67108864ll;                     // 67108864
    float* o_idx  = out + 134217728ll;                    // 524288
    float* o_w    = out + 134742016ll;                    // 12582912
    float* o_loss = out + 147324928ll;                    // 1
    float* o_cbn  = out + 147324929ll;                    // 3072
    float* o_ecs  = out + 147328001ll;                    // 24
    float* o_ees  = out + 147328025ll;                    // 3072

    float* acc = (float*)d_ws;

    vq_zero_acc<<<(ACC_FLOATS + TPB - 1) / TPB, TPB, 0, stream>>>(acc);
    vq_main<<<NROWS / RPB, TPB, 0, stream>>>(
        z_e, cb, o_soft, o_hard, o_idx, o_w, acc);
    vq_epilogue<<<1, TPB, 0, stream>>>(
        z_e, ema_cs, ema_es, ridx, acc, o_loss, o_cbn, o_ecs, o_ees);
}

// Round 5
// 636.379 us; speedup vs baseline: 1.1333x; 1.1333x over previous
//
#include <hip/hip_runtime.h>

#define KC 24
#define DC 128
#define TPB 256
#define NROWS 524288
#define RPB 256            // rows per block (4 waves x 64)
#define ZSTR 33            // zs row stride in floats: (33*l+j)%32=(l+j)%32 -> 2-way max
#define NSLICE 8           // accumulator slices (atomic contention relief)
#define SLICE_STRIDE 3104  // KC*DC + KC + 1 = 3097, padded
#define ACC_TOTAL (NSLICE * SLICE_STRIDE)

__global__ void vq_zero_acc(float* __restrict__ acc) {
    int i = blockIdx.x * blockDim.x + threadIdx.x;
    if (i < ACC_TOTAL) acc[i] = 0.0f;
}

__global__ __launch_bounds__(TPB) void vq_main(
    const float* __restrict__ z_e, const float* __restrict__ cb,
    float* __restrict__ o_soft, float* __restrict__ o_hard,
    float* __restrict__ o_idx, float* __restrict__ o_w,
    float* __restrict__ acc)
{
    __shared__ float cb_s[KC][DC + 5];      // stride 133: 5*id%32 injective for id<24
    __shared__ float wn_s[KC];
    __shared__ float ebin[KC][DC + 5];
    __shared__ float cnt_s[KC];
    __shared__ float loss_s;
    __shared__ float zs[4][64 * ZSTR];      // per-wave transpose buffer
    __shared__ int   idx_s[TPB];

    const int tid = threadIdx.x;
    const int w   = tid >> 6;
    const int l   = tid & 63;
    const int rg  = l >> 3;        // cooperative row sub-index
    const int sub = l & 7;
    const int sb4 = sub * 4;

    #pragma unroll 1
    for (int i = tid; i < KC * DC; i += TPB)
        (&cb_s[0][0])[(i >> 7) * (DC + 5) + (i & (DC - 1))] = cb[i];
    #pragma unroll 1
    for (int i = tid; i < KC * (DC + 5); i += TPB) (&ebin[0][0])[i] = 0.0f;
    if (tid < KC) cnt_s[tid] = 0.0f;
    if (tid == 0) loss_s = 0.0f;
    __syncthreads();
    if (tid < KC) {
        float s = 0.0f;
        #pragma unroll 1
        for (int d = 0; d < DC; ++d) s = fmaf(cb_s[tid][d], cb_s[tid][d], s);
        wn_s[tid] = s;
    }
    __syncthreads();

    const int rbase = blockIdx.x * RPB + w * 64;
    const float* gz = z_e + (size_t)rbase * DC;
    float* zw = &zs[w][0];

    float dv[KC];
    #pragma unroll
    for (int k = 0; k < KC; ++k) dv[k] = 0.0f;
    float zn = 0.0f;

    // ---- Pass A: cooperative load -> zs transpose -> row-per-lane dots ----
    float4 nxt[8];
    #pragma unroll
    for (int jj = 0; jj < 8; ++jj)
        nxt[jj] = *(const float4*)(gz + (size_t)(8 * jj + rg) * DC + sb4);

    #pragma unroll 1
    for (int c = 0; c < 4; ++c) {
        float4 curv[8];
        #pragma unroll
        for (int jj = 0; jj < 8; ++jj) curv[jj] = nxt[jj];
        if (c < 3) {
            #pragma unroll
            for (int jj = 0; jj < 8; ++jj)
                nxt[jj] = *(const float4*)(gz + (size_t)(8 * jj + rg) * DC
                                           + (c + 1) * 32 + sb4);
        }
        #pragma unroll
        for (int jj = 0; jj < 8; ++jj) {
            const int base = (8 * jj + rg) * ZSTR + sb4;
            zw[base + 0] = curv[jj].x; zw[base + 1] = curv[jj].y;
            zw[base + 2] = curv[jj].z; zw[base + 3] = curv[jj].w;
        }
        float zr[32];
        #pragma unroll
        for (int j = 0; j < 32; ++j) zr[j] = zw[l * ZSTR + j];
        #pragma unroll
        for (int i = 0; i < 8; ++i)
            zn = fmaf(zr[4*i], zr[4*i], fmaf(zr[4*i+1], zr[4*i+1],
                 fmaf(zr[4*i+2], zr[4*i+2], fmaf(zr[4*i+3], zr[4*i+3], zn))));
        #pragma unroll
        for (int k = 0; k < KC; ++k) {
            float s = dv[k];
            #pragma unroll
            for (int i = 0; i < 8; ++i) {
                const float4 wv = *(const float4*)(&cb_s[k][c * 32 + 4 * i]);
                s = fmaf(zr[4*i], wv.x, fmaf(zr[4*i+1], wv.y,
                    fmaf(zr[4*i+2], wv.z, fmaf(zr[4*i+3], wv.w, s))));
            }
            dv[k] = s;
        }
    }

    // ---- dists, argmin (first-min), softmax (per-lane, one row) ----
    int idx = 0;
    float best = 3.4e38f;
    #pragma unroll
    for (int k = 0; k < KC; ++k) {
        float d = (zn - 2.0f * dv[k]) + wn_s[k];
        dv[k] = d;
        if (d < best) { best = d; idx = k; }
    }
    float ssum = 0.0f;
    #pragma unroll
    for (int k = 0; k < KC; ++k) {
        float e = __expf(best - dv[k]);
        dv[k] = e;
        ssum += e;
    }
    const float inv = 1.0f / ssum;
    #pragma unroll
    for (int k = 0; k < KC; ++k) dv[k] *= inv;     // weights (kept for pass B)

    idx_s[tid] = idx;
    o_idx[rbase + l] = (float)idx;
    atomicAdd(&cnt_s[idx], 1.0f);
    {
        float loss_acc = best;
        #pragma unroll
        for (int off = 32; off > 0; off >>= 1)
            loss_acc += __shfl_down(loss_acc, off);
        if (l == 0) atomicAdd(&loss_s, loss_acc);
    }

    // weights: stage row -> cooperative coalesced store (6 x 1KB)
    #pragma unroll
    for (int k = 0; k < KC; ++k) zw[l * ZSTR + k] = dv[k];
    #pragma unroll
    for (int i = 0; i < 6; ++i) {
        const int off = 4 * (i * 64 + l);
        const int row = off / 24, col = off % 24;
        float4 v = make_float4(zw[row * ZSTR + col],     zw[row * ZSTR + col + 1],
                               zw[row * ZSTR + col + 2], zw[row * ZSTR + col + 3]);
        *(float4*)(o_w + (size_t)rbase * KC + off) = v;
    }

    // hoist the 8 cooperative row indices
    int ids[8];
    #pragma unroll
    for (int jj = 0; jj < 8; ++jj) ids[jj] = idx_s[w * 64 + 8 * jj + rg];

    // ---- Pass B: soft/hard/ebin, all VMEM cooperative ----
    #pragma unroll 1
    for (int c = 0; c < 4; ++c) {
        float4 zc[8];
        #pragma unroll
        for (int jj = 0; jj < 8; ++jj)
            zc[jj] = *(const float4*)(gz + (size_t)(8 * jj + rg) * DC
                                      + c * 32 + sb4);
        // soft chunk, row-per-lane with broadcast cb reads
        float sacc[32];
        #pragma unroll
        for (int j = 0; j < 32; ++j) sacc[j] = 0.0f;
        #pragma unroll
        for (int k = 0; k < KC; ++k) {
            const float wk = dv[k];
            #pragma unroll
            for (int i = 0; i < 8; ++i) {
                const float4 wv = *(const float4*)(&cb_s[k][c * 32 + 4 * i]);
                sacc[4*i+0] = fmaf(wk, wv.x, sacc[4*i+0]);
                sacc[4*i+1] = fmaf(wk, wv.y, sacc[4*i+1]);
                sacc[4*i+2] = fmaf(wk, wv.z, sacc[4*i+2]);
                sacc[4*i+3] = fmaf(wk, wv.w, sacc[4*i+3]);
            }
        }
        #pragma unroll
        for (int j = 0; j < 32; ++j) zw[l * ZSTR + j] = sacc[j];
        #pragma unroll
        for (int jj = 0; jj < 8; ++jj) {
            const int base = (8 * jj + rg) * ZSTR + sb4;
            float4 v = make_float4(zw[base], zw[base + 1], zw[base + 2], zw[base + 3]);
            *(float4*)(o_soft + (size_t)(rbase + 8 * jj + rg) * DC
                       + c * 32 + sb4) = v;
        }
        #pragma unroll
        for (int jj = 0; jj < 8; ++jj) {
            const float4 h = *(const float4*)(&cb_s[ids[jj]][c * 32 + sb4]);
            *(float4*)(o_hard + (size_t)(rbase + 8 * jj + rg) * DC
                       + c * 32 + sb4) = h;
        }
        #pragma unroll
        for (int jj = 0; jj < 8; ++jj) {
            const int d = c * 32 + sb4;
            atomicAdd(&ebin[ids[jj]][d + 0], zc[jj].x);
            atomicAdd(&ebin[ids[jj]][d + 1], zc[jj].y);
            atomicAdd(&ebin[ids[jj]][d + 2], zc[jj].z);
            atomicAdd(&ebin[ids[jj]][d + 3], zc[jj].w);
        }
    }
    __syncthreads();

    // flush to sliced global accumulator
    float* accs = acc + (size_t)(blockIdx.x & (NSLICE - 1)) * SLICE_STRIDE;
    #pragma unroll 1
    for (int i = tid; i < KC * DC; i += TPB)
        atomicAdd(&accs[i], (&ebin[0][0])[(i >> 7) * (DC + 5) + (i & (DC - 1))]);
    if (tid < KC) atomicAdd(&accs[KC * DC + tid], cnt_s[tid]);
    if (tid == 0) atomicAdd(&accs[KC * DC + KC], loss_s);
}

__global__ void vq_epilogue(
    const float* __restrict__ z_e, const float* __restrict__ ema_cs,
    const float* __restrict__ ema_es, const int* __restrict__ rand_idx,
    const float* __restrict__ acc,
    float* __restrict__ o_loss, float* __restrict__ o_cbn,
    float* __restrict__ o_ecs, float* __restrict__ o_ees)
{
    __shared__ float ecs_s[KC], sm_s[KC];
    __shared__ float n_sh;
    const int tid = threadIdx.x;
    if (tid < KC) {
        float csum = 0.0f;
        #pragma unroll
        for (int s = 0; s < NSLICE; ++s)
            csum += acc[s * SLICE_STRIDE + KC * DC + tid];
        ecs_s[tid] = 0.95f * ema_cs[tid] + 0.05f * csum;
    }
    __syncthreads();
    if (tid == 0) {
        float n = 0.0f;
        for (int k = 0; k < KC; ++k) n += ecs_s[k];
        n_sh = n;
    }
    __syncthreads();
    if (tid < KC) {
        float n = n_sh;
        sm_s[tid] = (ecs_s[tid] + 1e-5f) / (n + (float)KC * 1e-5f) * n;
    }
    __syncthreads();
    #pragma unroll 1
    for (int i = tid; i < KC * DC; i += TPB) {
        int k = i >> 7, d = i & (DC - 1);
        float esum = 0.0f;
        #pragma unroll
        for (int s = 0; s < NSLICE; ++s) esum += acc[s * SLICE_STRIDE + i];
        float ees = 0.95f * ema_es[i] + 0.05f * esum;
        float cbn = ees / sm_s[k];
        bool dead = ecs_s[k] < 0.1f;
        float rst = z_e[(size_t)rand_idx[k] * DC + d];
        o_cbn[i] = dead ? rst : cbn;
        o_ees[i] = dead ? rst : ees;
    }
    if (tid < KC) o_ecs[tid] = (ecs_s[tid] < 0.1f) ? 1.0f : ecs_s[tid];
    if (tid == 0) {
        float lsum = 0.0f;
        #pragma unroll
        for (int s = 0; s < NSLICE; ++s) lsum += acc[s * SLICE_STRIDE + KC * DC + KC];
        o_loss[0] = 1.5f * (lsum * (1.0f / 67108864.0f));
    }
}

extern "C" void kernel_launch(void* const* d_in, const int* in_sizes, int n_in,
                              void* d_out, int out_size, void* d_ws, size_t ws_size,
                              hipStream_t stream) {
    const float* z_e    = (const float*)d_in[0];
    const float* cb     = (const float*)d_in[1];
    const float* ema_cs = (const float*)d_in[2];
    const float* ema_es = (const float*)d_in[3];
    const int*   ridx   = (const int*)d_in[4];

    float* out = (float*)d_out;
    float* o_soft = out;                                  // 67108864
    float* o_hard = out + 67108864ll;                     // 67108864
    float* o_idx  = out + 134217728ll;                    // 524288
    float* o_w    = out + 134742016ll;                    // 12582912
    float* o_loss = out + 147324928ll;                    // 1
    float* o_cbn  = out + 147324929ll;                    // 3072
    float* o_ecs  = out + 147328001ll;                    // 24
    float* o_ees  = out + 147328025ll;                    // 3072

    float* acc = (float*)d_ws;

    vq_zero_acc<<<(ACC_TOTAL + TPB - 1) / TPB, TPB, 0, stream>>>(acc);
    vq_main<<<NROWS / RPB, TPB, 0, stream>>>(
        z_e, cb, o_soft, o_hard, o_idx, o_w, acc);
    vq_epilogue<<<1, TPB, 0, stream>>>(
        z_e, ema_cs, ema_es, ridx, acc, o_loss, o_cbn, o_ecs, o_ees);
}

// Round 6
// 539.889 us; speedup vs baseline: 1.3358x; 1.1787x over previous
//
#include <hip/hip_runtime.h>

#define KC 24
#define DC 128
#define TPB 256
#define NROWS 524288
#define CBS 132            // cb_s/ebin row stride (16B aligned)
#define NSLICE 8
#define SLICE_STRIDE 3104  // KC*DC + KC + 1 = 3097, padded
#define ACC_TOTAL (NSLICE * SLICE_STRIDE)

__global__ void vq_zero_acc(float* __restrict__ acc) {
    int i = blockIdx.x * blockDim.x + threadIdx.x;
    if (i < ACC_TOTAL) acc[i] = 0.0f;
}

__global__ __launch_bounds__(TPB, 4) void vq_main(
    const float* __restrict__ z_e, const float* __restrict__ cb,
    float* __restrict__ o_soft, float* __restrict__ o_hard,
    float* __restrict__ o_idx, float* __restrict__ o_w,
    float* __restrict__ acc)
{
    __shared__ float cb_s[KC][CBS];
    __shared__ float wn_s[KC];
    __shared__ float ebin[KC][CBS];
    __shared__ float cnt_s[KC];
    __shared__ float loss_s;

    const int tid = threadIdx.x;

    #pragma unroll 1
    for (int i = tid; i < KC * DC; i += TPB)
        cb_s[i >> 7][i & (DC - 1)] = cb[i];
    #pragma unroll 1
    for (int i = tid; i < KC * CBS; i += TPB) (&ebin[0][0])[i] = 0.0f;
    if (tid < KC) cnt_s[tid] = 0.0f;
    if (tid == 0) loss_s = 0.0f;
    __syncthreads();
    if (tid < KC) {
        float s = 0.0f;
        #pragma unroll 1
        for (int d = 0; d < DC; ++d) s = fmaf(cb_s[tid][d], cb_s[tid][d], s);
        wn_s[tid] = s;
    }
    __syncthreads();

    const int row = blockIdx.x * TPB + tid;
    const float* zp = z_e + (size_t)row * DC;

    float dv[KC];
    #pragma unroll
    for (int k = 0; k < KC; ++k) dv[k] = 0.0f;
    float zn = 0.0f;

    // ---- Pass A: 4 chunks of 32 floats; z discarded after each chunk ----
    #pragma unroll 1
    for (int c = 0; c < 4; ++c) {
        float4 a[8];
        #pragma unroll
        for (int i = 0; i < 8; ++i)
            a[i] = *(const float4*)(zp + c * 32 + 4 * i);
        #pragma unroll
        for (int i = 0; i < 8; ++i)
            zn = fmaf(a[i].x, a[i].x, fmaf(a[i].y, a[i].y,
                 fmaf(a[i].z, a[i].z, fmaf(a[i].w, a[i].w, zn))));
        #pragma unroll
        for (int k = 0; k < KC; ++k) {
            float s = dv[k];
            #pragma unroll
            for (int i = 0; i < 8; ++i) {
                const float4 wv = *(const float4*)(&cb_s[k][c * 32 + 4 * i]);
                s = fmaf(a[i].x, wv.x, fmaf(a[i].y, wv.y,
                    fmaf(a[i].z, wv.z, fmaf(a[i].w, wv.w, s))));
            }
            dv[k] = s;
        }
    }

    // ---- dists, argmin (first-min), softmax ----
    int idx = 0;
    float best = 3.4e38f;
    #pragma unroll
    for (int k = 0; k < KC; ++k) {
        float d = (zn - 2.0f * dv[k]) + wn_s[k];
        dv[k] = d;
        if (d < best) { best = d; idx = k; }
    }
    float ssum = 0.0f;
    #pragma unroll
    for (int k = 0; k < KC; ++k) {
        float e = __expf(best - dv[k]);
        dv[k] = e;
        ssum += e;
    }
    const float inv = 1.0f / ssum;
    #pragma unroll
    for (int k = 0; k < KC; ++k) dv[k] *= inv;   // weights

    // weights out: 6 float4 per row (96 B), L2 write-combines across rows
    #pragma unroll
    for (int q = 0; q < 6; ++q)
        *(float4*)(o_w + (size_t)row * KC + 4 * q) =
            make_float4(dv[4*q], dv[4*q+1], dv[4*q+2], dv[4*q+3]);
    o_idx[row] = (float)idx;
    atomicAdd(&cnt_s[idx], 1.0f);
    {
        float loss_acc = best;   // min-dist identity: ||z - c_idx||^2 == best
        #pragma unroll
        for (int off = 32; off > 0; off >>= 1)
            loss_acc += __shfl_down(loss_acc, off);
        if ((tid & 63) == 0) atomicAdd(&loss_s, loss_acc);
    }

    // ---- Pass B: reload z (L3-warm), soft/hard stores, ebin atomics ----
    #pragma unroll 1
    for (int c = 0; c < 4; ++c) {
        float4 a[8];
        #pragma unroll
        for (int i = 0; i < 8; ++i)
            a[i] = *(const float4*)(zp + c * 32 + 4 * i);
        float q[32];
        #pragma unroll
        for (int j = 0; j < 32; ++j) q[j] = 0.0f;
        #pragma unroll
        for (int k = 0; k < KC; ++k) {
            const float wk = dv[k];
            #pragma unroll
            for (int i = 0; i < 8; ++i) {
                const float4 wv = *(const float4*)(&cb_s[k][c * 32 + 4 * i]);
                q[4*i+0] = fmaf(wk, wv.x, q[4*i+0]);
                q[4*i+1] = fmaf(wk, wv.y, q[4*i+1]);
                q[4*i+2] = fmaf(wk, wv.z, q[4*i+2]);
                q[4*i+3] = fmaf(wk, wv.w, q[4*i+3]);
            }
        }
        #pragma unroll
        for (int i = 0; i < 8; ++i)
            *(float4*)(o_soft + (size_t)row * DC + c * 32 + 4 * i) =
                make_float4(q[4*i], q[4*i+1], q[4*i+2], q[4*i+3]);
        #pragma unroll
        for (int i = 0; i < 8; ++i) {
            const float4 h = *(const float4*)(&cb_s[idx][c * 32 + 4 * i]);
            *(float4*)(o_hard + (size_t)row * DC + c * 32 + 4 * i) = h;
        }
        #pragma unroll
        for (int i = 0; i < 8; ++i) {
            const int d = c * 32 + 4 * i;
            atomicAdd(&ebin[idx][d + 0], a[i].x);
            atomicAdd(&ebin[idx][d + 1], a[i].y);
            atomicAdd(&ebin[idx][d + 2], a[i].z);
            atomicAdd(&ebin[idx][d + 3], a[i].w);
        }
    }
    __syncthreads();

    // flush to sliced global accumulator
    float* accs = acc + (size_t)(blockIdx.x & (NSLICE - 1)) * SLICE_STRIDE;
    #pragma unroll 1
    for (int i = tid; i < KC * DC; i += TPB)
        atomicAdd(&accs[i], ebin[i >> 7][i & (DC - 1)]);
    if (tid < KC) atomicAdd(&accs[KC * DC + tid], cnt_s[tid]);
    if (tid == 0) atomicAdd(&accs[KC * DC + KC], loss_s);
}

__global__ void vq_epilogue(
    const float* __restrict__ z_e, const float* __restrict__ ema_cs,
    const float* __restrict__ ema_es, const int* __restrict__ rand_idx,
    const float* __restrict__ acc,
    float* __restrict__ o_loss, float* __restrict__ o_cbn,
    float* __restrict__ o_ecs, float* __restrict__ o_ees)
{
    __shared__ float ecs_s[KC], sm_s[KC];
    __shared__ float n_sh;
    const int tid = threadIdx.x;
    if (tid < KC) {
        float csum = 0.0f;
        #pragma unroll
        for (int s = 0; s < NSLICE; ++s)
            csum += acc[s * SLICE_STRIDE + KC * DC + tid];
        ecs_s[tid] = 0.95f * ema_cs[tid] + 0.05f * csum;
    }
    __syncthreads();
    if (tid == 0) {
        float n = 0.0f;
        for (int k = 0; k < KC; ++k) n += ecs_s[k];
        n_sh = n;
    }
    __syncthreads();
    if (tid < KC) {
        float n = n_sh;
        sm_s[tid] = (ecs_s[tid] + 1e-5f) / (n + (float)KC * 1e-5f) * n;
    }
    __syncthreads();
    #pragma unroll 1
    for (int i = tid; i < KC * DC; i += TPB) {
        int k = i >> 7, d = i & (DC - 1);
        float esum = 0.0f;
        #pragma unroll
        for (int s = 0; s < NSLICE; ++s) esum += acc[s * SLICE_STRIDE + i];
        float ees = 0.95f * ema_es[i] + 0.05f * esum;
        float cbn = ees / sm_s[k];
        bool dead = ecs_s[k] < 0.1f;
        float rst = z_e[(size_t)rand_idx[k] * DC + d];
        o_cbn[i] = dead ? rst : cbn;
        o_ees[i] = dead ? rst : ees;
    }
    if (tid < KC) o_ecs[tid] = (ecs_s[tid] < 0.1f) ? 1.0f : ecs_s[tid];
    if (tid == 0) {
        float lsum = 0.0f;
        #pragma unroll
        for (int s = 0; s < NSLICE; ++s)
            lsum += acc[s * SLICE_STRIDE + KC * DC + KC];
        o_loss[0] = 1.5f * (lsum * (1.0f / 67108864.0f));
    }
}

extern "C" void kernel_launch(void* const* d_in, const int* in_sizes, int n_in,
                              void* d_out, int out_size, void* d_ws, size_t ws_size,
                              hipStream_t stream) {
    const float* z_e    = (const float*)d_in[0];
    const float* cb     = (const float*)d_in[1];
    const float* ema_cs = (const float*)d_in[2];
    const float* ema_es = (const float*)d_in[3];
    const int*   ridx   = (const int*)d_in[4];

    float* out = (float*)d_out;
    float* o_soft = out;                                  // 67108864
    float* o_hard = out + 67108864ll;                     // 67108864
    float* o_idx  = out + 134217728ll;                    // 524288
    float* o_w    = out + 134742016ll;                    // 12582912
    float* o_loss = out + 147324928ll;                    // 1
    float* o_cbn  = out + 147324929ll;                    // 3072
    float* o_ecs  = out + 147328001ll;                    // 24
    float* o_ees  = out + 147328025ll;                    // 3072

    float* acc = (float*)d_ws;

    vq_zero_acc<<<(ACC_TOTAL + TPB - 1) / TPB, TPB, 0, stream>>>(acc);
    vq_main<<<NROWS / TPB, TPB, 0, stream>>>(
        z_e, cb, o_soft, o_hard, o_idx, o_w, acc);
    vq_epilogue<<<1, TPB, 0, stream>>>(
        z_e, ema_cs, ema_es, ridx, acc, o_loss, o_cbn, o_ecs, o_ees);
}